// Round 9
// baseline (348.321 us; speedup 1.0000x reference)
//
#include <hip/hip_runtime.h>
#include <stdint.h>

#define B_ 2
#define H_ 16
#define S_ 2048
#define D_ 128

typedef float f32x4 __attribute__((ext_vector_type(4)));
typedef float f32x16 __attribute__((ext_vector_type(16)));
typedef short bf16x8 __attribute__((ext_vector_type(8)));
typedef unsigned short u16x4 __attribute__((ext_vector_type(4)));
typedef int i32x4 __attribute__((ext_vector_type(4)));

__device__ __forceinline__ unsigned short f2bf(float x){
  union { float f; uint32_t u; } c; c.f = x;
  uint32_t u = c.u;
  uint32_t r = (u + 0x7FFFu + ((u >> 16) & 1u)) >> 16;
  return (unsigned short)r;
}

// ---- prep: K fp32 -> bf16 (same layout) ----
__global__ void kconv_kernel(const float* __restrict__ k, unsigned short* __restrict__ KB){
  size_t i = (size_t)blockIdx.x * 256 + threadIdx.x;   // 2,097,152 float4s exactly
  f32x4 v = __builtin_nontemporal_load(&((const f32x4*)k)[i]);
  u16x4 o; o[0]=f2bf(v.x); o[1]=f2bf(v.y); o[2]=f2bf(v.z); o[3]=f2bf(v.w);
  __builtin_nontemporal_store(o, &((u16x4*)KB)[i]);
}

// ---- prep: V fp32 [bh][t][d] -> VT bf16 [bh][d][t] ----
__global__ void vtrans_kernel(const float* __restrict__ v, unsigned short* __restrict__ VT){
  __shared__ float tile[64][73];          // pad 73: col-reads spread over banks
  int blk = blockIdx.x;                   // 2048 = 32 bh * 32 ttile * 2 dtile
  int bh = blk >> 6;
  int ts = (blk >> 1) & 31;
  int dsec = blk & 1;
  int t0 = ts*64, d0 = dsec*64;
  const float* vb = v + ((size_t)bh*S_ + t0)*D_ + d0;
  int tid = threadIdx.x;
  #pragma unroll
  for (int i=0;i<4;++i){
    int fi = i*256 + tid;                 // 1024 float4 per tile
    int r = fi >> 4;
    int c4 = (fi & 15) * 4;
    f32x4 val = __builtin_nontemporal_load((const f32x4*)(vb + (size_t)r*D_ + c4));
    tile[r][c4+0]=val.x; tile[r][c4+1]=val.y; tile[r][c4+2]=val.z; tile[r][c4+3]=val.w;
  }
  __syncthreads();
  unsigned short* ob = VT + ((size_t)bh*D_ + d0)*S_ + t0;
  #pragma unroll
  for (int i=0;i<4;++i){
    int ui = i*256 + tid;                 // 1024 ushort4 per tile
    int dr = ui >> 4;
    int tc = (ui & 15) * 4;
    u16x4 o;
    o[0] = f2bf(tile[tc+0][dr]);
    o[1] = f2bf(tile[tc+1][dr]);
    o[2] = f2bf(tile[tc+2][dr]);
    o[3] = f2bf(tile[tc+3][dr]);
    __builtin_nontemporal_store(o, (u16x4*)(ob + (size_t)dr*S_ + tc));
  }
}

// ---- prep: mask int32 [b][s][t] -> bitmask u64 [b][s][32 words] ----
__global__ void maskprep_kernel(const int* __restrict__ mask, unsigned long long* __restrict__ bits){
  int row = blockIdx.x;                   // B_*S_ = 4096 rows
  const int* mrow = mask + (size_t)row*S_;
  int w = threadIdx.x >> 6;
  int lane = threadIdx.x & 63;
  #pragma unroll
  for (int i=0;i<8;++i){
    int t = i*256 + threadIdx.x;
    unsigned long long bm = __ballot(__builtin_nontemporal_load(&mrow[t]) != 0);
    if (lane == 0) bits[(size_t)row*32 + i*4 + w] = bm;
  }
}

// ---- main fused: 32x32x16 MFMA, swapped QK^T (lane-local rows), R8 pipeline ----
__launch_bounds__(512, 4)
__global__ void fused_kernel(const float* __restrict__ q,
                             const unsigned long long* __restrict__ bits,
                             const unsigned short* __restrict__ KB,
                             const unsigned short* __restrict__ VT,
                             float* __restrict__ outp,
                             float* __restrict__ c_ws)
{
  __shared__ __align__(16) unsigned char Ksm[64*256];  // [t][128 bf16], 4-bit XOR swz
  __shared__ __align__(16) unsigned char Vsm[64*256];  // [d>>1][(d&1)*128B + t*2B], 4-bit XOR swz
  __shared__ float lred[8][32];
  const int tid = threadIdx.x;
  const int lane = tid & 63;
  const int w = tid >> 6;                  // 8 waves
  const int l32 = lane & 31;
  const int lh = lane >> 5;                // 0/1

  // bijective XCD swizzle: grid=512, 8 XCDs -> 64 consecutive logical blocks/XCD
  const int orig = blockIdx.x;
  const int blk = (orig & 7) * 64 + (orig >> 3);
  const int bh = blk >> 4;
  const int qt = blk & 15;
  const int b = bh >> 4;
  const int s0 = qt * 128;
  const int r = w >> 1;                    // q-row group 0..3 (32 rows each)
  const int cQ = w & 1;                    // t-half (QK) / d-pair (PV)
  const int qrow = s0 + 32*r + l32;        // this lane's q-row

  const float QS = 1.4426950408889634f / 11.313708498984761f;  // log2(e)/TEMP

  // Q as B-fragments (col=lane&31=q-row, k=d): qf[m] = Q[qrow][16m+8lh .. +8]
  bf16x8 qf[8];
  {
    const float* qp = q + ((size_t)bh*S_ + qrow)*D_ + 8*lh;
    #pragma unroll
    for (int m=0; m<8; ++m){
      f32x4 a0 = __builtin_nontemporal_load((const f32x4*)(qp + 16*m));
      f32x4 a1 = __builtin_nontemporal_load((const f32x4*)(qp + 16*m + 4));
      bf16x8 f;
      f[0]=(short)f2bf(a0.x*QS); f[1]=(short)f2bf(a0.y*QS);
      f[2]=(short)f2bf(a0.z*QS); f[3]=(short)f2bf(a0.w*QS);
      f[4]=(short)f2bf(a1.x*QS); f[5]=(short)f2bf(a1.y*QS);
      f[6]=(short)f2bf(a1.z*QS); f[7]=(short)f2bf(a1.w*QS);
      qf[m] = f;
    }
  }

  f32x16 Wacc[2];
  #pragma unroll
  for (int n=0;n<2;++n)
    #pragma unroll
    for (int e=0;e<16;++e) Wacc[n][e] = 0.f;
  float lsum = 0.f;

  const unsigned char* Kgb = (const unsigned char*)(KB + (size_t)bh*S_*D_);
  const unsigned char* Vgb = (const unsigned char*)(VT + (size_t)bh*D_*S_);
  const unsigned long long* bitsb = bits + (size_t)b*S_*32 + (size_t)qrow*32;

  // staging: K 64 rows x 16 slots, V 128 d x 8 t-slots; 2 chunks/thread each
  int kr_[2], kcb_[2], vrow_[2], vslot_[2]; size_t vsrc_[2];
  #pragma unroll
  for (int i=0;i<2;++i){
    int c = i*512 + tid;
    kr_[i]  = c >> 4;
    kcb_[i] = c & 15;
    int d   = c >> 3;
    int ts  = c & 7;
    vrow_[i]  = d >> 1;
    vslot_[i] = ((d&1)<<3) | ts;
    vsrc_[i]  = (size_t)d*(S_*2) + ts*16;
  }
  i32x4 kst[2], vst[2];

  auto loadstage = [&](int it){
    #pragma unroll
    for (int i=0;i<2;++i)
      kst[i] = *(const i32x4*)(Kgb + (size_t)it*16384 + kr_[i]*256 + (kcb_[i]<<4));
    #pragma unroll
    for (int i=0;i<2;++i)
      vst[i] = *(const i32x4*)(Vgb + vsrc_[i] + (size_t)it*128);
  };
  auto writestage = [&](){
    #pragma unroll
    for (int i=0;i<2;++i)
      *(i32x4*)(&Ksm[kr_[i]*256 + ((kcb_[i] ^ (kr_[i]&15))<<4)]) = kst[i];
    #pragma unroll
    for (int i=0;i<2;++i)
      *(i32x4*)(&Vsm[vrow_[i]*256 + ((vslot_[i] ^ (vrow_[i]&15))<<4)]) = vst[i];
  };

  loadstage(0);

  for (int it=0; it<32; ++it){
    __syncthreads();            // full drain: staged regs arrived, prior reads done
    writestage();

    unsigned long long mb = bitsb[it];   // 1 u64/lane: issued BEFORE prefetch (FIFO)
    if (it+1 < 32) loadstage(it+1);      // prefetch stays in flight through compute

    asm volatile("s_waitcnt lgkmcnt(0)" ::: "memory");   // ds_writes visible (NOT vmcnt)
    __builtin_amdgcn_sched_barrier(0);
    __builtin_amdgcn_s_barrier();                        // raw: no vmcnt drain
    __builtin_amdgcn_sched_barrier(0);

    // QK (swapped): S^T tile 32t x 32q; A = K from LDS, B = Q regs
    f32x16 Sacc;
    #pragma unroll
    for (int e=0;e<16;++e) Sacc[e] = 0.f;
    const int trow = 32*cQ + l32;
    const int tbase = trow*256;
    const int txr = trow & 15;
    __builtin_amdgcn_s_setprio(1);
    #pragma unroll
    for (int m=0; m<8; ++m){
      int slot = (2*m + lh) ^ txr;
      bf16x8 kf = *(const bf16x8*)(&Ksm[tbase + (slot<<4)]);
      Sacc = __builtin_amdgcn_mfma_f32_32x32x16_bf16(kf, qf[m], Sacc, 0,0,0);
    }
    __builtin_amdgcn_s_setprio(0);

    // stats: lane owns q-row qrow; S^T C-layout: col=l32 (q), row=t=(reg&3)+8*(reg>>2)+4lh
    // masked -> exp2(0)=1.0 == exp(1e-9) in fp32; no max needed (|s*log2e| <~ 17)
    uint32_t mw = (uint32_t)(mb >> (32*cQ + 4*lh));
    #pragma unroll
    for (int reg=0; reg<16; ++reg){
      const int tb = (reg&3) + 8*(reg>>2);
      float x = ((mw >> tb) & 1u) ? 0.f : Sacc[reg];
      lsum += __builtin_amdgcn_exp2f(x);
    }

    // PV A-frags (mask 0/1 bf16) from the same u64: A[row=q=l32][k=t=16m2+8lh+j]
    unsigned long long ms = mb >> (8*lh);
    uint32_t mlo = (uint32_t)ms, mhi = (uint32_t)(ms >> 32);
    bf16x8 am[4];
    #pragma unroll
    for (int m2=0; m2<4; ++m2){
      uint32_t bt = ((m2 < 2 ? mlo : mhi) >> (16*(m2&1))) & 0xFFu;
      union { bf16x8 v; uint32_t u[4]; } pk;
      #pragma unroll
      for (int j2=0; j2<4; ++j2){
        pk.u[j2] = (((bt>>(2*j2))&1u) ? 0x3F80u : 0u)
                 | (((bt>>(2*j2+1))&1u) ? 0x3F800000u : 0u);
      }
      am[m2] = pk.v;
    }

    // PV: W[q][d] += mask @ V; two 32-wide d-tiles per wave, B = V^T from LDS
    #pragma unroll
    for (int n=0; n<2; ++n){
      const int dd = 32*(2*cQ + n) + l32;
      const int vbase = (dd>>1)*256;
      const int vx = (dd&1)<<3;
      const int vxr = (dd>>1)&15;
      __builtin_amdgcn_s_setprio(1);
      #pragma unroll
      for (int m2=0; m2<4; ++m2){
        int slot = (vx | (2*m2 + lh)) ^ vxr;
        bf16x8 vf = *(const bf16x8*)(&Vsm[vbase + (slot<<4)]);
        Wacc[n] = __builtin_amdgcn_mfma_f32_32x32x16_bf16(am[m2], vf, Wacc[n], 0,0,0);
      }
      __builtin_amdgcn_s_setprio(0);
    }
  }

  // combine l: lane-halves (disjoint t-patterns, same q-row), then c-half waves
  lsum += __shfl_xor(lsum, 32);
  if (lane < 32) lred[w][l32] = lsum;
  __syncthreads();

  float cval[16];
  #pragma unroll
  for (int reg=0; reg<16; ++reg){
    int crow = (reg&3) + 8*(reg>>2) + 4*lh;
    cval[reg] = 1.0f / (lred[2*r][crow] + lred[2*r+1][crow]);
  }
  if (tid < 128){
    int rr = tid >> 5;
    float cc = 1.0f / (lred[2*rr][tid&31] + lred[2*rr+1][tid&31]);
    c_ws[(size_t)bh*S_ + s0 + tid] = cc;
  }
  // out = c * W ; W C-layout: col=l32 (d), row=(reg&3)+8*(reg>>2)+4lh (q)
  #pragma unroll
  for (int n=0; n<2; ++n){
    const int dd = 32*(2*cQ + n) + l32;
    #pragma unroll
    for (int reg=0; reg<16; ++reg){
      int row = s0 + 32*r + (reg&3) + 8*(reg>>2) + 4*lh;
      __builtin_nontemporal_store(cval[reg]*Wacc[n][reg],
                                  &outp[((size_t)bh*S_ + row)*D_ + dd]);
    }
  }
}

// ---- atten output: atten[b,h,s,:] = c[b,h,s] * maskbit[b,s,:] ----
__global__ void atten_kernel(const unsigned long long* __restrict__ bits,
                             const float* __restrict__ c_ws,
                             float* __restrict__ atten){
  int blk = blockIdx.x;            // B_*S_ = 4096 blocks
  int bq = blk >> 11;
  int s  = blk & 2047;
  __shared__ float csm[16];
  if (threadIdx.x < 16)
    csm[threadIdx.x] = c_ws[((size_t)(bq*H_ + threadIdx.x))*S_ + s];
  __syncthreads();
  const unsigned long long* wrow = bits + ((size_t)bq*S_ + s)*32;
  for (int i = threadIdx.x; i < S_/4; i += 256){
    unsigned long long wv = wrow[i >> 4];
    uint32_t nib = (uint32_t)(wv >> ((i & 15)*4)) & 0xFu;
    #pragma unroll
    for (int h=0; h<H_; ++h){
      float c = csm[h];
      f32x4 o = { (nib&1u)?c:0.f, (nib&2u)?c:0.f, (nib&4u)?c:0.f, (nib&8u)?c:0.f };
      __builtin_nontemporal_store(o, ((f32x4*)(atten + (((size_t)(bq*H_ + h)*S_ + s)*S_))) + i);
    }
  }
}

extern "C" void kernel_launch(void* const* d_in, const int* in_sizes, int n_in,
                              void* d_out, int out_size, void* d_ws, size_t ws_size,
                              hipStream_t stream){
  const float* q = (const float*)d_in[0];
  const float* k = (const float*)d_in[1];
  const float* v = (const float*)d_in[2];
  const int* mask = (const int*)d_in[3];
  float* outp = (float*)d_out;
  float* atten = outp + (size_t)B_*H_*S_*D_;

  unsigned short* KB = (unsigned short*)d_ws;                         // 16.78 MB
  unsigned short* VT = KB + (size_t)B_*H_*S_*D_;                      // 16.78 MB
  float* c_ws = (float*)(VT + (size_t)B_*H_*S_*D_);                   // 0.26 MB
  unsigned long long* bits = (unsigned long long*)(c_ws + (size_t)B_*H_*S_);  // 1.05 MB

  hipLaunchKernelGGL(maskprep_kernel, dim3(4096), dim3(256), 0, stream, mask, bits);
  hipLaunchKernelGGL(kconv_kernel,  dim3(8192), dim3(256), 0, stream, k, KB);
  hipLaunchKernelGGL(vtrans_kernel, dim3(2048), dim3(256), 0, stream, v, VT);
  hipLaunchKernelGGL(fused_kernel,  dim3(512),  dim3(512), 0, stream, q, bits, KB, VT, outp, c_ws);
  hipLaunchKernelGGL(atten_kernel,  dim3(4096), dim3(256), 0, stream, bits, c_ws, atten);
}

// Round 10
// 262.819 us; speedup vs baseline: 1.3253x; 1.3253x over previous
//
#include <hip/hip_runtime.h>
#include <stdint.h>

#define B_ 2
#define H_ 16
#define S_ 2048
#define D_ 128

typedef float f32x4 __attribute__((ext_vector_type(4)));
typedef float f32x16 __attribute__((ext_vector_type(16)));
typedef short bf16x8 __attribute__((ext_vector_type(8)));
typedef unsigned short u16x4 __attribute__((ext_vector_type(4)));
typedef int i32x4 __attribute__((ext_vector_type(4)));

__device__ __forceinline__ unsigned short f2bf(float x){
  union { float f; uint32_t u; } c; c.f = x;
  uint32_t u = c.u;
  uint32_t r = (u + 0x7FFFu + ((u >> 16) & 1u)) >> 16;
  return (unsigned short)r;
}

__device__ __forceinline__ void gload_lds16(const void* g, void* l){
  __builtin_amdgcn_global_load_lds(
      (const __attribute__((address_space(1))) unsigned int*)g,
      (__attribute__((address_space(3))) unsigned int*)l, 16, 0, 0);
}

// ---- prep: K fp32 -> bf16 (same layout) ----
__global__ void kconv_kernel(const float* __restrict__ k, unsigned short* __restrict__ KB){
  size_t i = (size_t)blockIdx.x * 256 + threadIdx.x;   // 2,097,152 float4s exactly
  f32x4 v = __builtin_nontemporal_load(&((const f32x4*)k)[i]);
  u16x4 o; o[0]=f2bf(v.x); o[1]=f2bf(v.y); o[2]=f2bf(v.z); o[3]=f2bf(v.w);
  __builtin_nontemporal_store(o, &((u16x4*)KB)[i]);
}

// ---- prep: V fp32 [bh][t][d] -> VT bf16 [bh][d][t] ----
__global__ void vtrans_kernel(const float* __restrict__ v, unsigned short* __restrict__ VT){
  __shared__ float tile[64][73];          // pad 73: col-reads spread over banks
  int blk = blockIdx.x;                   // 2048 = 32 bh * 32 ttile * 2 dtile
  int bh = blk >> 6;
  int ts = (blk >> 1) & 31;
  int dsec = blk & 1;
  int t0 = ts*64, d0 = dsec*64;
  const float* vb = v + ((size_t)bh*S_ + t0)*D_ + d0;
  int tid = threadIdx.x;
  #pragma unroll
  for (int i=0;i<4;++i){
    int fi = i*256 + tid;                 // 1024 float4 per tile
    int r = fi >> 4;
    int c4 = (fi & 15) * 4;
    f32x4 val = __builtin_nontemporal_load((const f32x4*)(vb + (size_t)r*D_ + c4));
    tile[r][c4+0]=val.x; tile[r][c4+1]=val.y; tile[r][c4+2]=val.z; tile[r][c4+3]=val.w;
  }
  __syncthreads();
  unsigned short* ob = VT + ((size_t)bh*D_ + d0)*S_ + t0;
  #pragma unroll
  for (int i=0;i<4;++i){
    int ui = i*256 + tid;                 // 1024 ushort4 per tile
    int dr = ui >> 4;
    int tc = (ui & 15) * 4;
    u16x4 o;
    o[0] = f2bf(tile[tc+0][dr]);
    o[1] = f2bf(tile[tc+1][dr]);
    o[2] = f2bf(tile[tc+2][dr]);
    o[3] = f2bf(tile[tc+3][dr]);
    __builtin_nontemporal_store(o, (u16x4*)(ob + (size_t)dr*S_ + tc));
  }
}

// ---- prep: mask int32 [b][s][t] -> bitmask u64 [b][s][32 words] ----
__global__ void maskprep_kernel(const int* __restrict__ mask, unsigned long long* __restrict__ bits){
  int row = blockIdx.x;                   // B_*S_ = 4096 rows
  const int* mrow = mask + (size_t)row*S_;
  int w = threadIdx.x >> 6;
  int lane = threadIdx.x & 63;
  #pragma unroll
  for (int i=0;i<8;++i){
    int t = i*256 + threadIdx.x;
    unsigned long long bm = __ballot(__builtin_nontemporal_load(&mrow[t]) != 0);
    if (lane == 0) bits[(size_t)row*32 + i*4 + w] = bm;
  }
}

// ---- main fused: 32x32x16 MFMA, gload_lds dbuf pipeline, register-lean ----
__launch_bounds__(512, 4)
__global__ void fused_kernel(const float* __restrict__ q,
                             const unsigned long long* __restrict__ bits,
                             const unsigned short* __restrict__ KB,
                             const unsigned short* __restrict__ VT,
                             float* __restrict__ outp,
                             float* __restrict__ c_ws)
{
  __shared__ __align__(16) unsigned char Ksm[2][16384];  // [t][128 bf16], 4-bit XOR swz content
  __shared__ __align__(16) unsigned char Vsm[2][16384];  // [d>>1][(d&1)*128B + t*2B], swz content
  __shared__ float lred[8][32];
  const int tid = threadIdx.x;
  const int lane = tid & 63;
  const int w = tid >> 6;                  // 8 waves
  const int l32 = lane & 31;
  const int lh = lane >> 5;                // 0/1

  // bijective XCD swizzle: grid=512, 8 XCDs -> 64 consecutive logical blocks/XCD
  const int orig = blockIdx.x;
  const int blk = (orig & 7) * 64 + (orig >> 3);
  const int bh = blk >> 4;
  const int qt = blk & 15;
  const int b = bh >> 4;
  const int s0 = qt * 128;
  const int r = w >> 1;                    // q-row group 0..3 (32 rows each)
  const int cQ = w & 1;                    // t-half (QK) / d-pair (PV)
  const int qrow = s0 + 32*r + l32;        // this lane's q-row

  const float QS = 1.4426950408889634f / 11.313708498984761f;  // log2(e)/TEMP

  // Q as B-fragments (col=lane&31=q-row, k=d): qf[m] = Q[qrow][16m+8lh .. +8]
  bf16x8 qf[8];
  {
    const float* qp = q + ((size_t)bh*S_ + qrow)*D_ + 8*lh;
    #pragma unroll
    for (int m=0; m<8; ++m){
      f32x4 a0 = __builtin_nontemporal_load((const f32x4*)(qp + 16*m));
      f32x4 a1 = __builtin_nontemporal_load((const f32x4*)(qp + 16*m + 4));
      bf16x8 f;
      f[0]=(short)f2bf(a0.x*QS); f[1]=(short)f2bf(a0.y*QS);
      f[2]=(short)f2bf(a0.z*QS); f[3]=(short)f2bf(a0.w*QS);
      f[4]=(short)f2bf(a1.x*QS); f[5]=(short)f2bf(a1.y*QS);
      f[6]=(short)f2bf(a1.z*QS); f[7]=(short)f2bf(a1.w*QS);
      qf[m] = f;
    }
  }

  f32x16 Wacc[2];
  #pragma unroll
  for (int n=0;n<2;++n)
    #pragma unroll
    for (int e=0;e<16;++e) Wacc[n][e] = 0.f;
  float lsum = 0.f;

  const unsigned char* Kgb = (const unsigned char*)(KB + (size_t)bh*S_*D_);
  const unsigned char* Vgb = (const unsigned char*)(VT + (size_t)bh*D_*S_);
  const unsigned long long* bitsb = bits + (size_t)b*S_*32 + (size_t)qrow*32;

  // staging: 16 chunks of 1KB each for K and V; wave w stages chunks {2w, 2w+1}.
  // LDS dest is linear (chunk base + lane*16); global source is inverse-swizzled.
  uint32_t koff[2], voff[2];
  int kbase[2];
  {
    int lq = lane >> 4, ls = lane & 15;
    #pragma unroll
    for (int i=0;i<2;++i){
      int c = 2*w + i;
      kbase[i] = c*1024;
      int rr = c*4 + lq;                   // dest row (0..63)
      int ss = ls ^ (rr & 15);             // unswizzled slot
      koff[i] = (uint32_t)(rr*256 + ss*16);           // K[rr][d-slot ss]
      int d  = rr*2 + (ss>>3);
      int ts = ss & 7;
      voff[i] = (uint32_t)(d*(S_*2) + ts*16);         // V[d][t-slot ts]
    }
  }

  // prologue: mask word first (older in vmcnt FIFO), then stage tile 0
  unsigned long long mbn = bitsb[0];
  #pragma unroll
  for (int i=0;i<2;++i){
    gload_lds16(Kgb + koff[i], &Ksm[0][kbase[i]]);
    gload_lds16(Vgb + voff[i], &Vsm[0][kbase[i]]);
  }

  int cur = 0;
  for (int it=0; it<32; ++it){
    // stage(cur) + mask(it) were issued one full compute phase ago
    asm volatile("s_waitcnt vmcnt(0)" ::: "memory");
    __builtin_amdgcn_sched_barrier(0);
    __builtin_amdgcn_s_barrier();
    __builtin_amdgcn_sched_barrier(0);

    unsigned long long mb = mbn;
    if (it+1 < 32){
      mbn = bitsb[it+1];                   // issued BEFORE stage (older in FIFO)
      const unsigned char* Kp = Kgb + (size_t)(it+1)*16384;
      const unsigned char* Vp = Vgb + (size_t)(it+1)*128;
      #pragma unroll
      for (int i=0;i<2;++i){
        gload_lds16(Kp + koff[i], &Ksm[cur^1][kbase[i]]);
        gload_lds16(Vp + voff[i], &Vsm[cur^1][kbase[i]]);
      }
      __builtin_amdgcn_sched_barrier(0);   // pin stage issue before compute
    }

    // QK (swapped): S^T tile 32t x 32q; A = K from LDS, B = Q regs
    f32x16 Sacc;
    #pragma unroll
    for (int e=0;e<16;++e) Sacc[e] = 0.f;
    const int trow = 32*cQ + l32;
    const unsigned char* kb = &Ksm[cur][trow*256];
    const int txr = trow & 15;
    __builtin_amdgcn_s_setprio(1);
    #pragma unroll
    for (int m=0; m<8; ++m){
      int slot = (2*m + lh) ^ txr;
      bf16x8 kf = *(const bf16x8*)(kb + (slot<<4));
      Sacc = __builtin_amdgcn_mfma_f32_32x32x16_bf16(kf, qf[m], Sacc, 0,0,0);
    }
    __builtin_amdgcn_s_setprio(0);

    // stats: lane owns q-row; S^T C-layout: col=l32 (q), row=t=(reg&3)+8*(reg>>2)+4lh
    // masked -> exp2(0)=1.0 == exp(1e-9) in fp32; no max needed (|s*log2e| <~ 17)
    uint32_t mw = (uint32_t)(mb >> (32*cQ + 4*lh));
    #pragma unroll
    for (int reg=0; reg<16; ++reg){
      const int tb = (reg&3) + 8*(reg>>2);
      float x = ((mw >> tb) & 1u) ? 0.f : Sacc[reg];
      lsum += __builtin_amdgcn_exp2f(x);
    }

    // PV: W[q][d] += mask @ V; A (mask 0/1 bf16) built per m2, B = V^T from LDS
    unsigned long long ms = mb >> (8*lh);
    uint32_t mlo = (uint32_t)ms, mhi = (uint32_t)(ms >> 32);
    #pragma unroll
    for (int m2=0; m2<4; ++m2){
      uint32_t bt = ((m2 < 2 ? mlo : mhi) >> (16*(m2&1))) & 0xFFu;
      union { bf16x8 v; uint32_t u[4]; } pk;
      #pragma unroll
      for (int j2=0; j2<4; ++j2){
        pk.u[j2] = (((bt>>(2*j2))&1u) ? 0x3F80u : 0u)
                 | (((bt>>(2*j2+1))&1u) ? 0x3F800000u : 0u);
      }
      __builtin_amdgcn_s_setprio(1);
      #pragma unroll
      for (int n=0; n<2; ++n){
        const int dd = 32*(2*cQ + n) + l32;
        int slot = ((((dd&1)<<3) | (2*m2 + lh)) ^ ((dd>>1)&15));
        bf16x8 vf = *(const bf16x8*)(&Vsm[cur][(dd>>1)*256 + (slot<<4)]);
        Wacc[n] = __builtin_amdgcn_mfma_f32_32x32x16_bf16(pk.v, vf, Wacc[n], 0,0,0);
      }
      __builtin_amdgcn_s_setprio(0);
    }
    cur ^= 1;
  }

  // combine l: lane-halves (disjoint t-patterns, same q-row), then t-half waves
  lsum += __shfl_xor(lsum, 32);
  if (lane < 32) lred[w][l32] = lsum;
  __syncthreads();

  if (tid < 128){
    int rr = tid >> 5;
    float cc = 1.0f / (lred[2*rr][tid&31] + lred[2*rr+1][tid&31]);
    c_ws[(size_t)bh*S_ + s0 + tid] = cc;
  }
  // out = c * W ; W C-layout: col=l32 (d), row=(reg&3)+8*(reg>>2)+4lh (q)
  #pragma unroll
  for (int reg=0; reg<16; ++reg){
    int crow = (reg&3) + 8*(reg>>2) + 4*lh;
    float cv = 1.0f / (lred[2*r][crow] + lred[2*r+1][crow]);
    int row = s0 + 32*r + crow;
    #pragma unroll
    for (int n=0; n<2; ++n){
      const int dd = 32*(2*cQ + n) + l32;
      __builtin_nontemporal_store(cv*Wacc[n][reg],
                                  &outp[((size_t)bh*S_ + row)*D_ + dd]);
    }
  }
}

// ---- atten output: atten[b,h,s,:] = c[b,h,s] * maskbit[b,s,:] ----
__global__ void atten_kernel(const unsigned long long* __restrict__ bits,
                             const float* __restrict__ c_ws,
                             float* __restrict__ atten){
  int blk = blockIdx.x;            // B_*S_ = 4096 blocks
  int bq = blk >> 11;
  int s  = blk & 2047;
  __shared__ float csm[16];
  if (threadIdx.x < 16)
    csm[threadIdx.x] = c_ws[((size_t)(bq*H_ + threadIdx.x))*S_ + s];
  __syncthreads();
  const unsigned long long* wrow = bits + ((size_t)bq*S_ + s)*32;
  for (int i = threadIdx.x; i < S_/4; i += 256){
    unsigned long long wv = wrow[i >> 4];
    uint32_t nib = (uint32_t)(wv >> ((i & 15)*4)) & 0xFu;
    #pragma unroll
    for (int h=0; h<H_; ++h){
      float c = csm[h];
      f32x4 o = { (nib&1u)?c:0.f, (nib&2u)?c:0.f, (nib&4u)?c:0.f, (nib&8u)?c:0.f };
      __builtin_nontemporal_store(o, ((f32x4*)(atten + (((size_t)(bq*H_ + h)*S_ + s)*S_))) + i);
    }
  }
}

extern "C" void kernel_launch(void* const* d_in, const int* in_sizes, int n_in,
                              void* d_out, int out_size, void* d_ws, size_t ws_size,
                              hipStream_t stream){
  const float* q = (const float*)d_in[0];
  const float* k = (const float*)d_in[1];
  const float* v = (const float*)d_in[2];
  const int* mask = (const int*)d_in[3];
  float* outp = (float*)d_out;
  float* atten = outp + (size_t)B_*H_*S_*D_;

  unsigned short* KB = (unsigned short*)d_ws;                         // 16.78 MB
  unsigned short* VT = KB + (size_t)B_*H_*S_*D_;                      // 16.78 MB
  float* c_ws = (float*)(VT + (size_t)B_*H_*S_*D_);                   // 0.26 MB
  unsigned long long* bits = (unsigned long long*)(c_ws + (size_t)B_*H_*S_);  // 1.05 MB

  hipLaunchKernelGGL(maskprep_kernel, dim3(4096), dim3(256), 0, stream, mask, bits);
  hipLaunchKernelGGL(kconv_kernel,  dim3(8192), dim3(256), 0, stream, k, KB);
  hipLaunchKernelGGL(vtrans_kernel, dim3(2048), dim3(256), 0, stream, v, VT);
  hipLaunchKernelGGL(fused_kernel,  dim3(512),  dim3(512), 0, stream, q, bits, KB, VT, outp, c_ws);
  hipLaunchKernelGGL(atten_kernel,  dim3(4096), dim3(256), 0, stream, bits, c_ws, atten);
}

// Round 11
// 222.980 us; speedup vs baseline: 1.5621x; 1.1787x over previous
//
#include <hip/hip_runtime.h>
#include <stdint.h>

#define B_ 2
#define H_ 16
#define S_ 2048
#define D_ 128

typedef float f32x4 __attribute__((ext_vector_type(4)));
typedef float f32x16 __attribute__((ext_vector_type(16)));
typedef short bf16x8 __attribute__((ext_vector_type(8)));
typedef unsigned short u16x4 __attribute__((ext_vector_type(4)));
typedef int i32x4 __attribute__((ext_vector_type(4)));

__device__ __forceinline__ unsigned short f2bf(float x){
  union { float f; uint32_t u; } c; c.f = x;
  uint32_t u = c.u;
  uint32_t r = (u + 0x7FFFu + ((u >> 16) & 1u)) >> 16;
  return (unsigned short)r;
}

__device__ __forceinline__ void gload_lds16(const void* g, void* l){
  __builtin_amdgcn_global_load_lds(
      (const __attribute__((address_space(1))) unsigned int*)g,
      (__attribute__((address_space(3))) unsigned int*)l, 16, 0, 0);
}

// ---- merged prep: K->bf16 | V->VT bf16 | mask->bits, partitioned by blockIdx ----
__global__ void prep_kernel(const float* __restrict__ k, const float* __restrict__ v,
                            const int* __restrict__ mask,
                            unsigned short* __restrict__ KB, unsigned short* __restrict__ VT,
                            unsigned long long* __restrict__ bits){
  __shared__ float tile[64][73];          // vtrans only; pad 73 breaks bank conflicts
  const int blk = blockIdx.x;
  const int tid = threadIdx.x;
  if (blk < 8192){
    // K fp32 -> bf16
    size_t i = (size_t)blk * 256 + tid;   // 2,097,152 float4s exactly
    f32x4 val = __builtin_nontemporal_load(&((const f32x4*)k)[i]);
    u16x4 o; o[0]=f2bf(val.x); o[1]=f2bf(val.y); o[2]=f2bf(val.z); o[3]=f2bf(val.w);
    __builtin_nontemporal_store(o, &((u16x4*)KB)[i]);
  } else if (blk < 10240){
    // V fp32 [bh][t][d] -> VT bf16 [bh][d][t]
    int b2 = blk - 8192;                  // 2048 = 32 bh * 32 ttile * 2 dtile
    int bh = b2 >> 6;
    int ts = (b2 >> 1) & 31;
    int dsec = b2 & 1;
    int t0 = ts*64, d0 = dsec*64;
    const float* vb = v + ((size_t)bh*S_ + t0)*D_ + d0;
    #pragma unroll
    for (int i=0;i<4;++i){
      int fi = i*256 + tid;
      int r = fi >> 4;
      int c4 = (fi & 15) * 4;
      f32x4 val = __builtin_nontemporal_load((const f32x4*)(vb + (size_t)r*D_ + c4));
      tile[r][c4+0]=val.x; tile[r][c4+1]=val.y; tile[r][c4+2]=val.z; tile[r][c4+3]=val.w;
    }
    __syncthreads();
    unsigned short* ob = VT + ((size_t)bh*D_ + d0)*S_ + t0;
    #pragma unroll
    for (int i=0;i<4;++i){
      int ui = i*256 + tid;
      int dr = ui >> 4;
      int tc = (ui & 15) * 4;
      u16x4 o;
      o[0] = f2bf(tile[tc+0][dr]);
      o[1] = f2bf(tile[tc+1][dr]);
      o[2] = f2bf(tile[tc+2][dr]);
      o[3] = f2bf(tile[tc+3][dr]);
      __builtin_nontemporal_store(o, (u16x4*)(ob + (size_t)dr*S_ + tc));
    }
  } else {
    // mask int32 [b][s][t] -> bitmask u64 [b][s][32]
    int row = blk - 10240;                // 4096 rows
    const int* mrow = mask + (size_t)row*S_;
    int w = tid >> 6;
    int lane = tid & 63;
    #pragma unroll
    for (int i=0;i<8;++i){
      int t = i*256 + tid;
      unsigned long long bm = __ballot(__builtin_nontemporal_load(&mrow[t]) != 0);
      if (lane == 0) bits[(size_t)row*32 + i*4 + w] = bm;
    }
  }
}

// ---- main fused: 32x32x16 MFMA, gload_lds dbuf pipeline, atten fused in epilogue ----
__launch_bounds__(512, 4)
__global__ void fused_kernel(const float* __restrict__ q,
                             const unsigned long long* __restrict__ bits,
                             const unsigned short* __restrict__ KB,
                             const unsigned short* __restrict__ VT,
                             float* __restrict__ outp,
                             float* __restrict__ atten)
{
  __shared__ __align__(16) unsigned char Ksm[2][16384];  // [t][128 bf16], 4-bit XOR swz content
  __shared__ __align__(16) unsigned char Vsm[2][16384];  // [d>>1][(d&1)*128B + t*2B], swz content
  __shared__ float lred[8][32];
  const int tid = threadIdx.x;
  const int lane = tid & 63;
  const int w = tid >> 6;                  // 8 waves
  const int l32 = lane & 31;
  const int lh = lane >> 5;                // 0/1

  // bijective XCD swizzle: grid=512, 8 XCDs -> 64 consecutive logical blocks/XCD
  const int orig = blockIdx.x;
  const int blk = (orig & 7) * 64 + (orig >> 3);
  const int bh = blk >> 4;
  const int qt = blk & 15;
  const int b = bh >> 4;
  const int s0 = qt * 128;
  const int r = w >> 1;                    // q-row group 0..3 (32 rows each)
  const int cQ = w & 1;                    // t-half (QK) / d-pair (PV)
  const int qrow = s0 + 32*r + l32;        // this lane's q-row

  const float QS = 1.4426950408889634f / 11.313708498984761f;  // log2(e)/TEMP

  // Q as B-fragments (col=lane&31=q-row, k=d): qf[m] = Q[qrow][16m+8lh .. +8]
  bf16x8 qf[8];
  {
    const float* qp = q + ((size_t)bh*S_ + qrow)*D_ + 8*lh;
    #pragma unroll
    for (int m=0; m<8; ++m){
      f32x4 a0 = __builtin_nontemporal_load((const f32x4*)(qp + 16*m));
      f32x4 a1 = __builtin_nontemporal_load((const f32x4*)(qp + 16*m + 4));
      bf16x8 f;
      f[0]=(short)f2bf(a0.x*QS); f[1]=(short)f2bf(a0.y*QS);
      f[2]=(short)f2bf(a0.z*QS); f[3]=(short)f2bf(a0.w*QS);
      f[4]=(short)f2bf(a1.x*QS); f[5]=(short)f2bf(a1.y*QS);
      f[6]=(short)f2bf(a1.z*QS); f[7]=(short)f2bf(a1.w*QS);
      qf[m] = f;
    }
  }

  f32x16 Wacc[2];
  #pragma unroll
  for (int n=0;n<2;++n)
    #pragma unroll
    for (int e=0;e<16;++e) Wacc[n][e] = 0.f;
  float lsum = 0.f;

  const unsigned char* Kgb = (const unsigned char*)(KB + (size_t)bh*S_*D_);
  const unsigned char* Vgb = (const unsigned char*)(VT + (size_t)bh*D_*S_);
  const unsigned long long* bitsb = bits + (size_t)b*S_*32 + (size_t)qrow*32;

  // staging: 16 chunks of 1KB each for K and V; wave w stages chunks {2w, 2w+1}.
  // LDS dest is linear (chunk base + lane*16); global source is inverse-swizzled.
  uint32_t koff[2], voff[2];
  int kbase[2];
  {
    int lq = lane >> 4, ls = lane & 15;
    #pragma unroll
    for (int i=0;i<2;++i){
      int c = 2*w + i;
      kbase[i] = c*1024;
      int rr = c*4 + lq;                   // dest row (0..63)
      int ss = ls ^ (rr & 15);             // unswizzled slot
      koff[i] = (uint32_t)(rr*256 + ss*16);           // K[rr][d-slot ss]
      int d  = rr*2 + (ss>>3);
      int ts = ss & 7;
      voff[i] = (uint32_t)(d*(S_*2) + ts*16);         // V[d][t-slot ts]
    }
  }

  // prologue: mask word first (older in vmcnt FIFO), then stage tile 0
  unsigned long long mbn = bitsb[0];
  #pragma unroll
  for (int i=0;i<2;++i){
    gload_lds16(Kgb + koff[i], &Ksm[0][kbase[i]]);
    gload_lds16(Vgb + voff[i], &Vsm[0][kbase[i]]);
  }

  int cur = 0;
  for (int it=0; it<32; ++it){
    // stage(cur) + mask(it) were issued one full compute phase ago
    asm volatile("s_waitcnt vmcnt(0)" ::: "memory");
    __builtin_amdgcn_sched_barrier(0);
    __builtin_amdgcn_s_barrier();
    __builtin_amdgcn_sched_barrier(0);

    unsigned long long mb = mbn;
    if (it+1 < 32){
      mbn = bitsb[it+1];                   // issued BEFORE stage (older in FIFO)
      const unsigned char* Kp = Kgb + (size_t)(it+1)*16384;
      const unsigned char* Vp = Vgb + (size_t)(it+1)*128;
      #pragma unroll
      for (int i=0;i<2;++i){
        gload_lds16(Kp + koff[i], &Ksm[cur^1][kbase[i]]);
        gload_lds16(Vp + voff[i], &Vsm[cur^1][kbase[i]]);
      }
      __builtin_amdgcn_sched_barrier(0);   // pin stage issue before compute
    }

    // QK (swapped): S^T tile 32t x 32q; A = K from LDS, B = Q regs
    f32x16 Sacc;
    #pragma unroll
    for (int e=0;e<16;++e) Sacc[e] = 0.f;
    const int trow = 32*cQ + l32;
    const unsigned char* kb = &Ksm[cur][trow*256];
    const int txr = trow & 15;
    __builtin_amdgcn_s_setprio(1);
    #pragma unroll
    for (int m=0; m<8; ++m){
      int slot = (2*m + lh) ^ txr;
      bf16x8 kf = *(const bf16x8*)(kb + (slot<<4));
      Sacc = __builtin_amdgcn_mfma_f32_32x32x16_bf16(kf, qf[m], Sacc, 0,0,0);
    }
    __builtin_amdgcn_s_setprio(0);

    // stats: lane owns q-row; S^T C-layout: col=l32 (q), row=t=(reg&3)+8*(reg>>2)+4lh
    // masked -> exp2(0)=1.0 == exp(1e-9) in fp32; no max needed (|s*log2e| <~ 17)
    uint32_t mw = (uint32_t)(mb >> (32*cQ + 4*lh));
    #pragma unroll
    for (int reg=0; reg<16; ++reg){
      const int tb = (reg&3) + 8*(reg>>2);
      float x = ((mw >> tb) & 1u) ? 0.f : Sacc[reg];
      lsum += __builtin_amdgcn_exp2f(x);
    }

    // PV: W[q][d] += mask @ V; A (mask 0/1 bf16) built per m2, B = V^T from LDS
    unsigned long long ms = mb >> (8*lh);
    uint32_t mlo = (uint32_t)ms, mhi = (uint32_t)(ms >> 32);
    #pragma unroll
    for (int m2=0; m2<4; ++m2){
      uint32_t bt = ((m2 < 2 ? mlo : mhi) >> (16*(m2&1))) & 0xFFu;
      union { bf16x8 v; uint32_t u[4]; } pk;
      #pragma unroll
      for (int j2=0; j2<4; ++j2){
        pk.u[j2] = (((bt>>(2*j2))&1u) ? 0x3F80u : 0u)
                 | (((bt>>(2*j2+1))&1u) ? 0x3F800000u : 0u);
      }
      __builtin_amdgcn_s_setprio(1);
      #pragma unroll
      for (int n=0; n<2; ++n){
        const int dd = 32*(2*cQ + n) + l32;
        int slot = ((((dd&1)<<3) | (2*m2 + lh)) ^ ((dd>>1)&15));
        bf16x8 vf = *(const bf16x8*)(&Vsm[cur][(dd>>1)*256 + (slot<<4)]);
        Wacc[n] = __builtin_amdgcn_mfma_f32_32x32x16_bf16(pk.v, vf, Wacc[n], 0,0,0);
      }
      __builtin_amdgcn_s_setprio(0);
    }
    cur ^= 1;
  }

  // combine l: lane-halves (disjoint t-patterns, same q-row), then t-half waves
  lsum += __shfl_xor(lsum, 32);
  if (lane < 32) lred[w][l32] = lsum;
  __syncthreads();                         // all waves done with Ksm/Vsm + lred ready

  // ---- epilogue setup: reuse Ksm for this block's bit rows, Vsm for c ----
  unsigned long long* bitlds = (unsigned long long*)&Ksm[0][0];    // 4096 u64 = 32 KB
  float* csm = (float*)&Vsm[0][0];                                 // 128 floats
  {
    const i32x4* bsrc = (const i32x4*)(bits + ((size_t)b*S_ + s0)*32);
    i32x4* bdst = (i32x4*)bitlds;
    #pragma unroll
    for (int i=0;i<4;++i)
      bdst[i*512 + tid] = bsrc[i*512 + tid];     // 2048 i32x4 = 32 KB, coalesced
    if (tid < 128){
      int rr = tid >> 5;
      csm[tid] = 1.0f / (lred[2*rr][tid&31] + lred[2*rr+1][tid&31]);
    }
  }

  // out = c * W ; W C-layout: col=l32 (d), row=(reg&3)+8*(reg>>2)+4lh (q)
  #pragma unroll
  for (int reg=0; reg<16; ++reg){
    int crow = (reg&3) + 8*(reg>>2) + 4*lh;
    float cv = 1.0f / (lred[2*r][crow] + lred[2*r+1][crow]);
    int row = s0 + 32*r + crow;
    #pragma unroll
    for (int n=0; n<2; ++n){
      const int dd = 32*(2*cQ + n) + l32;
      __builtin_nontemporal_store(cv*Wacc[n][reg],
                                  &outp[((size_t)bh*S_ + row)*D_ + dd]);
    }
  }

  __syncthreads();                         // bitlds + csm visible

  // atten rows [s0, s0+128): atten[bh][s][t] = c[s] * bit[t]; 8 KB per j, coalesced
  {
    f32x4* abase = (f32x4*)(atten + ((size_t)bh*S_ + s0)*S_);
    const int word = tid >> 4;             // 32 words per row
    const int sh = (tid & 15)*4;
    for (int j=0; j<128; ++j){
      float c = csm[j];
      unsigned long long wv = bitlds[j*32 + word];
      uint32_t nib = (uint32_t)(wv >> sh) & 0xFu;
      f32x4 o = { (nib&1u)?c:0.f, (nib&2u)?c:0.f, (nib&4u)?c:0.f, (nib&8u)?c:0.f };
      __builtin_nontemporal_store(o, &abase[j*512 + tid]);
    }
  }
}

extern "C" void kernel_launch(void* const* d_in, const int* in_sizes, int n_in,
                              void* d_out, int out_size, void* d_ws, size_t ws_size,
                              hipStream_t stream){
  const float* q = (const float*)d_in[0];
  const float* k = (const float*)d_in[1];
  const float* v = (const float*)d_in[2];
  const int* mask = (const int*)d_in[3];
  float* outp = (float*)d_out;
  float* atten = outp + (size_t)B_*H_*S_*D_;

  unsigned short* KB = (unsigned short*)d_ws;                         // 16.78 MB
  unsigned short* VT = KB + (size_t)B_*H_*S_*D_;                      // 16.78 MB
  unsigned long long* bits = (unsigned long long*)(VT + (size_t)B_*H_*S_*D_);  // 1.05 MB

  hipLaunchKernelGGL(prep_kernel,  dim3(14336), dim3(256), 0, stream, k, v, mask, KB, VT, bits);
  hipLaunchKernelGGL(fused_kernel, dim3(512),   dim3(512), 0, stream, q, bits, KB, VT, outp, atten);
}